// Round 1
// baseline (398.611 us; speedup 1.0000x reference)
//
#include <hip/hip_runtime.h>
#include <stdint.h>

// Problem constants: B=32, L=128, A=64, C=128, KT=3
// scale = sqrt(L + A - 2) = sqrt(190)

__device__ __forceinline__ uint32_t f2bf(float f) {
    union { float f; uint32_t u; } v; v.f = f;
    return (v.u + 0x7FFFu + ((v.u >> 16) & 1u)) >> 16;  // RNE
}
__device__ __forceinline__ float bf2f(uint32_t h) {
    union { uint32_t u; float f; } v; v.u = h << 16; return v.f;
}

// W [co][ci][kt] -> Wt [kt][ci][co]  (49152 floats)
__global__ void wt_kernel(const float* __restrict__ W, float* __restrict__ Wt) {
    int o = blockIdx.x * 256 + threadIdx.x;          // exact: 192*256 = 49152
    int co = o & 127, ci = (o >> 7) & 127, kt = o >> 14;
    Wt[o] = W[(co * 128 + ci) * 3 + kt];
}

// One block per (b,t): computes y[b, :, t, :] = conv + bias  (tile 64a x 128co, K=384)
// Writes y in bf16 ([b][t][a][c] layout) and agent_sum[b][t][c] (in-block reduce over a).
__global__ __launch_bounds__(256) void conv_kernel(
    const float* __restrict__ x, const float* __restrict__ Wt,
    const float* __restrict__ bias, uint16_t* __restrict__ y16,
    float* __restrict__ asum)
{
    __shared__ float Xs[32 * 64];    // [kk][a]
    __shared__ float Ws[32 * 128];   // [kk][co]
    __shared__ float red[16 * 128];  // [tx][co]

    const int tid = threadIdx.x;
    const int bt  = blockIdx.x;       // b*128 + t
    const int t   = bt & 127;
    const int b   = bt >> 7;

    const int tx = tid & 15, ty = tid >> 4;
    const int a0 = tx * 4, co0 = ty * 8;

    float acc[4][8];
    #pragma unroll
    for (int i = 0; i < 4; ++i)
        #pragma unroll
        for (int j = 0; j < 8; ++j) acc[i][j] = 0.f;

    const int la = tid & 63, lg = tid >> 6;        // X staging: a, k-group
    const int wc = (tid & 31) * 4, wk = tid >> 5;  // W staging: co, k

    for (int kc = 0; kc < 12; ++kc) {
        const int kt  = kc >> 2;
        const int ci0 = (kc & 3) << 5;
        const int tsrc = t + kt - 1;
        const float m = ((unsigned)tsrc < 128u) ? 1.f : 0.f;   // zero-pad in time
        const int tcl = tsrc < 0 ? 0 : (tsrc > 127 ? 127 : tsrc);
        const float* xrow = x + (((size_t)(b * 128 + tcl)) * 64 + la) * 128 + ci0;
        #pragma unroll
        for (int rep = 0; rep < 2; ++rep) {
            const int kk = lg * 4 + rep * 16;
            float4 v = *(const float4*)(xrow + kk);   // coalesced 16B/lane
            Xs[(kk + 0) * 64 + la] = v.x * m;         // consecutive-a writes: no conflict
            Xs[(kk + 1) * 64 + la] = v.y * m;
            Xs[(kk + 2) * 64 + la] = v.z * m;
            Xs[(kk + 3) * 64 + la] = v.w * m;
        }
        const float* wrow = Wt + (size_t)(kt * 128 + ci0) * 128;
        #pragma unroll
        for (int rep = 0; rep < 4; ++rep) {
            const int kk = wk + rep * 8;
            *(float4*)(Ws + kk * 128 + wc) = *(const float4*)(wrow + kk * 128 + wc);
        }
        __syncthreads();
        #pragma unroll
        for (int kk = 0; kk < 32; ++kk) {
            const float4 xa = *(const float4*)(Xs + kk * 64 + a0);
            const float4 w0 = *(const float4*)(Ws + kk * 128 + co0);
            const float4 w1 = *(const float4*)(Ws + kk * 128 + co0 + 4);
            const float xv[4] = {xa.x, xa.y, xa.z, xa.w};
            const float wv[8] = {w0.x, w0.y, w0.z, w0.w, w1.x, w1.y, w1.z, w1.w};
            #pragma unroll
            for (int ai = 0; ai < 4; ++ai)
                #pragma unroll
                for (int cj = 0; cj < 8; ++cj)
                    acc[ai][cj] = fmaf(xv[ai], wv[cj], acc[ai][cj]);
        }
        __syncthreads();
    }

    const float4 bb0 = *(const float4*)(bias + co0);
    const float4 bb1 = *(const float4*)(bias + co0 + 4);
    const float bv[8] = {bb0.x, bb0.y, bb0.z, bb0.w, bb1.x, bb1.y, bb1.z, bb1.w};

    float p[8];
    #pragma unroll
    for (int j = 0; j < 8; ++j) p[j] = 0.f;

    #pragma unroll
    for (int ai = 0; ai < 4; ++ai) {
        uint32_t pk[4];
        #pragma unroll
        for (int j = 0; j < 4; ++j) {
            float lo = acc[ai][2 * j]     + bv[2 * j];
            float hi = acc[ai][2 * j + 1] + bv[2 * j + 1];
            p[2 * j] += lo; p[2 * j + 1] += hi;
            pk[j] = f2bf(lo) | (f2bf(hi) << 16);
        }
        uint16_t* yp = y16 + (((size_t)bt) * 64 + (a0 + ai)) * 128 + co0;
        *(uint4*)yp = make_uint4(pk[0], pk[1], pk[2], pk[3]);
    }
    // agent_sum: reduce partials over the 16 tx groups
    #pragma unroll
    for (int j = 0; j < 8; ++j) red[tx * 128 + co0 + j] = p[j];
    __syncthreads();
    if (tid < 128) {
        float s = 0.f;
        #pragma unroll
        for (int i = 0; i < 16; ++i) s += red[i * 128 + tid];
        asum[(size_t)bt * 128 + tid] = s;
    }
}

// time_sum[b][a][c] = sum_t y[b][t][a][c]
__global__ __launch_bounds__(128) void tsum_kernel(
    const uint16_t* __restrict__ y16, float* __restrict__ tsum)
{
    const int c = threadIdx.x;
    const int blk = blockIdx.x;            // b*64 + a
    const int a = blk & 63, b = blk >> 6;
    const uint16_t* p = y16 + (((size_t)b * 128) * 64 + a) * 128 + c;
    float s = 0.f;
    #pragma unroll 8
    for (int t = 0; t < 128; ++t) s += bf2f(p[(size_t)t * 8192]);
    tsum[(size_t)blk * 128 + c] = s;
}

// out = relu((asum + tsum - y)/sqrt(190) + x), all in [B,L,A,C]
__global__ __launch_bounds__(256) void final_kernel(
    const float* __restrict__ x, const uint16_t* __restrict__ y16,
    const float* __restrict__ asum, const float* __restrict__ tsum,
    float* __restrict__ out)
{
    const float inv = 0.07254762501100116f;  // 1/sqrt(190)
    const size_t base = ((size_t)blockIdx.x * 256 + threadIdx.x) * 8;
    const int c0 = (int)(base & 127);
    const int a  = (int)((base >> 7) & 63);
    const int bt = (int)(base >> 13);
    const int b  = bt >> 7;

    const uint4  yv = *(const uint4*)(y16 + base);
    const float4 x0 = *(const float4*)(x + base);
    const float4 x1 = *(const float4*)(x + base + 4);
    const float* ap = asum + (size_t)bt * 128 + c0;
    const float* tp = tsum + ((size_t)b * 64 + a) * 128 + c0;
    const float4 as0 = *(const float4*)ap,  as1 = *(const float4*)(ap + 4);
    const float4 ts0 = *(const float4*)tp,  ts1 = *(const float4*)(tp + 4);

    float y[8];
    y[0] = bf2f(yv.x & 0xFFFFu); y[1] = bf2f(yv.x >> 16);
    y[2] = bf2f(yv.y & 0xFFFFu); y[3] = bf2f(yv.y >> 16);
    y[4] = bf2f(yv.z & 0xFFFFu); y[5] = bf2f(yv.z >> 16);
    y[6] = bf2f(yv.w & 0xFFFFu); y[7] = bf2f(yv.w >> 16);
    const float av[8] = {as0.x, as0.y, as0.z, as0.w, as1.x, as1.y, as1.z, as1.w};
    const float tv[8] = {ts0.x, ts0.y, ts0.z, ts0.w, ts1.x, ts1.y, ts1.z, ts1.w};
    const float xv[8] = {x0.x, x0.y, x0.z, x0.w, x1.x, x1.y, x1.z, x1.w};
    float o[8];
    #pragma unroll
    for (int j = 0; j < 8; ++j) {
        float g = (av[j] + tv[j] - y[j]) * inv + xv[j];
        o[j] = g > 0.f ? g : 0.f;
    }
    *(float4*)(out + base)     = make_float4(o[0], o[1], o[2], o[3]);
    *(float4*)(out + base + 4) = make_float4(o[4], o[5], o[6], o[7]);
}

extern "C" void kernel_launch(void* const* d_in, const int* in_sizes, int n_in,
                              void* d_out, int out_size, void* d_ws, size_t ws_size,
                              hipStream_t stream) {
    const float* x    = (const float*)d_in[0];
    const float* W    = (const float*)d_in[1];
    const float* bias = (const float*)d_in[2];
    float* out = (float*)d_out;

    // workspace layout (needs ~70.5 MB):
    //   y16 : 32*128*64*128 bf16  = 67108864 B
    //   Wt  : 49152 f32           =   196608 B
    //   asum: 32*128*128 f32      =  2097152 B
    //   tsum: 32*64*128 f32       =  1048576 B
    char* ws = (char*)d_ws;
    uint16_t* y16 = (uint16_t*)(ws);
    float* Wt     = (float*)(ws + 67108864);
    float* asum   = (float*)(ws + 67108864 + 196608);
    float* tsum   = (float*)(ws + 67108864 + 196608 + 2097152);

    wt_kernel  <<<192,   256, 0, stream>>>(W, Wt);
    conv_kernel<<<4096,  256, 0, stream>>>(x, Wt, bias, y16, asum);
    tsum_kernel<<<2048,  128, 0, stream>>>(y16, tsum);
    final_kernel<<<16384, 256, 0, stream>>>(x, y16, asum, tsum, out);
}

// Round 2
// 146.342 us; speedup vs baseline: 2.7238x; 2.7238x over previous
//
#include <hip/hip_runtime.h>
#include <stdint.h>

// B=32, L=128, A=64, C=128, KT=3.  scale = sqrt(190).
// Conv as GEMM: rows r = t*64+a; tap d reads x rows r + (d-1)*64.

typedef __attribute__((ext_vector_type(8))) short bf16x8;
typedef __attribute__((ext_vector_type(4))) float f32x4;

__device__ __forceinline__ uint32_t f2bf(float f) {
    union { float f; uint32_t u; } v; v.f = f;
    return (v.u + 0x7FFFu + ((v.u >> 16) & 1u)) >> 16;  // RNE
}
__device__ __forceinline__ float bf2f(uint32_t h) {
    union { uint32_t u; float f; } v; v.u = h << 16; return v.f;
}

// W fp32 [co][ci][kt] -> Wpack bf16 in exact MFMA B-fragment order:
// Wpack[((d*4+ks)*8 + nt)*64 + lane][i]  with ci = ks*32+(lane>>4)*8+i, co = nt*16+(lane&15)
__global__ void wpack_kernel(const float* __restrict__ W, uint16_t* __restrict__ wp) {
    int o = blockIdx.x * 256 + threadIdx.x;   // 192*256 = 49152 exact
    int i = o & 7, lane = (o >> 3) & 63, nt = (o >> 9) & 7, ks = (o >> 12) & 3, d = o >> 14;
    int ci = ks * 32 + (lane >> 4) * 8 + i;
    int co = nt * 16 + (lane & 15);
    wp[o] = (uint16_t)f2bf(W[(co * 128 + ci) * 3 + d]);
}

// One block per (b, t-pair): BM=128 rows x BN=128 co.  Slab = 256 rows (halo +-64).
__global__ __launch_bounds__(256, 2) void conv_kernel(
    const float* __restrict__ x, const uint16_t* __restrict__ wp,
    const float* __restrict__ bias, uint16_t* __restrict__ y16,
    float* __restrict__ asum)
{
    __shared__ __align__(16) uint16_t slab[256 * 128];   // 64 KB, XOR-swizzled

    const int tid = threadIdx.x;
    const int bid = blockIdx.x;            // b*64 + tg
    const int b = bid >> 6, t0 = (bid & 63) * 2;

    // ---- stage x slab (fp32 -> bf16, swizzled), rows r0-64 .. r0+191 ----
    {
        const int rb = tid >> 4, cg = tid & 15;          // row-base, 16B-chunk
        #pragma unroll
        for (int k = 0; k < 16; ++k) {
            const int row  = k * 16 + rb;                // 0..255
            const int tloc = t0 + (row >> 6) - 1;
            uint4 o4 = make_uint4(0, 0, 0, 0);
            if ((unsigned)tloc < 128u) {
                const float* src = x + (((size_t)(b * 128 + tloc) * 64 + (row & 63)) * 128) + cg * 8;
                float4 v0 = *(const float4*)src;
                float4 v1 = *(const float4*)(src + 4);
                o4.x = f2bf(v0.x) | (f2bf(v0.y) << 16);
                o4.y = f2bf(v0.z) | (f2bf(v0.w) << 16);
                o4.z = f2bf(v1.x) | (f2bf(v1.y) << 16);
                o4.w = f2bf(v1.z) | (f2bf(v1.w) << 16);
            }
            const int el = (row * 128 + cg * 8) ^ ((row & 7) << 3);
            *(uint4*)(slab + el) = o4;
        }
    }
    __syncthreads();

    // ---- MFMA loop: no barriers, no HBM (A from LDS, B from L2) ----
    const int lane = tid & 63, wid = tid >> 6;
    const int wm = wid >> 1, wn = wid & 1;      // wave quadrant of 128x128
    const int lr = lane & 15, lg = lane >> 4;

    f32x4 acc[4][4];
    #pragma unroll
    for (int mi = 0; mi < 4; ++mi)
        #pragma unroll
        for (int ni = 0; ni < 4; ++ni) acc[mi][ni] = (f32x4)0.f;

    #pragma unroll
    for (int d = 0; d < 3; ++d) {
        #pragma unroll
        for (int g = 0; g < 4; ++g) {
            bf16x8 af[4], bf[4];
            const int ci = g * 32 + lg * 8;
            #pragma unroll
            for (int mi = 0; mi < 4; ++mi) {
                const int row = (wm + d) * 64 + mi * 16 + lr;
                af[mi] = *(const bf16x8*)(slab + ((row * 128 + ci) ^ ((row & 7) << 3)));
            }
            #pragma unroll
            for (int ni = 0; ni < 4; ++ni)
                bf[ni] = *(const bf16x8*)(wp + ((((d * 4 + g) * 8 + wn * 4 + ni) * 64 + lane) << 3));
            #pragma unroll
            for (int mi = 0; mi < 4; ++mi)
                #pragma unroll
                for (int ni = 0; ni < 4; ++ni)
                    acc[mi][ni] = __builtin_amdgcn_mfma_f32_16x16x32_bf16(af[mi], bf[ni], acc[mi][ni], 0, 0, 0);
        }
    }

    // ---- epilogue: y16 store + agent_sum (in-wave, shfl reduce) ----
    const size_t ybase = (size_t)bid * 128 * 128;   // r0*128
    #pragma unroll
    for (int ni = 0; ni < 4; ++ni) {
        const int col = wn * 64 + ni * 16 + lr;
        const float bv = bias[col];
        float p = 0.f;
        #pragma unroll
        for (int mi = 0; mi < 4; ++mi) {
            #pragma unroll
            for (int j = 0; j < 4; ++j) {
                const float av = acc[mi][ni][j];
                p += av;
                const int row = wm * 64 + mi * 16 + lg * 4 + j;
                y16[ybase + (size_t)row * 128 + col] = (uint16_t)f2bf(av + bv);
            }
        }
        p += __shfl_xor(p, 16);
        p += __shfl_xor(p, 32);
        if (lg == 0)
            asum[(size_t)(b * 128 + t0 + wm) * 128 + col] = p + 64.f * bv;
    }
}

// time_sum[b][a][c] = sum_t y[b][t][a][c]; 1 KB/wave coalesced reads
__global__ __launch_bounds__(256) void tsum_kernel(
    const uint16_t* __restrict__ y16, float* __restrict__ tsum)
{
    const int g = blockIdx.x * 256 + threadIdx.x;   // 128 blocks: 32768 = 32b*64a*16oct
    const int c0 = (g & 15) * 8;
    const int a  = (g >> 4) & 63;
    const int b  = g >> 10;
    const uint16_t* p = y16 + ((size_t)(b * 128) * 64 + a) * 128 + c0;
    float s[8];
    #pragma unroll
    for (int j = 0; j < 8; ++j) s[j] = 0.f;
    #pragma unroll 4
    for (int t = 0; t < 128; ++t) {
        const uint4 v = *(const uint4*)(p + (size_t)t * 8192);
        s[0] += bf2f(v.x & 0xFFFFu); s[1] += bf2f(v.x >> 16);
        s[2] += bf2f(v.y & 0xFFFFu); s[3] += bf2f(v.y >> 16);
        s[4] += bf2f(v.z & 0xFFFFu); s[5] += bf2f(v.z >> 16);
        s[6] += bf2f(v.w & 0xFFFFu); s[7] += bf2f(v.w >> 16);
    }
    float* q = tsum + (size_t)(b * 64 + a) * 128 + c0;
    *(float4*)q       = make_float4(s[0], s[1], s[2], s[3]);
    *(float4*)(q + 4) = make_float4(s[4], s[5], s[6], s[7]);
}

// out = relu((asum + tsum - y)/sqrt(190) + x), [B,L,A,C]
__global__ __launch_bounds__(256) void final_kernel(
    const float* __restrict__ x, const uint16_t* __restrict__ y16,
    const float* __restrict__ asum, const float* __restrict__ tsum,
    float* __restrict__ out)
{
    const float inv = 0.07254762501100116f;  // 1/sqrt(190)
    const size_t base = ((size_t)blockIdx.x * 256 + threadIdx.x) * 8;
    const int c0 = (int)(base & 127);
    const int a  = (int)((base >> 7) & 63);
    const int bt = (int)(base >> 13);
    const int b  = bt >> 7;

    const uint4  yv = *(const uint4*)(y16 + base);
    const float4 x0 = *(const float4*)(x + base);
    const float4 x1 = *(const float4*)(x + base + 4);
    const float* ap = asum + (size_t)bt * 128 + c0;
    const float* tp = tsum + ((size_t)b * 64 + a) * 128 + c0;
    const float4 as0 = *(const float4*)ap,  as1 = *(const float4*)(ap + 4);
    const float4 ts0 = *(const float4*)tp,  ts1 = *(const float4*)(tp + 4);

    float y[8];
    y[0] = bf2f(yv.x & 0xFFFFu); y[1] = bf2f(yv.x >> 16);
    y[2] = bf2f(yv.y & 0xFFFFu); y[3] = bf2f(yv.y >> 16);
    y[4] = bf2f(yv.z & 0xFFFFu); y[5] = bf2f(yv.z >> 16);
    y[6] = bf2f(yv.w & 0xFFFFu); y[7] = bf2f(yv.w >> 16);
    const float av[8] = {as0.x, as0.y, as0.z, as0.w, as1.x, as1.y, as1.z, as1.w};
    const float tv[8] = {ts0.x, ts0.y, ts0.z, ts0.w, ts1.x, ts1.y, ts1.z, ts1.w};
    const float xv[8] = {x0.x, x0.y, x0.z, x0.w, x1.x, x1.y, x1.z, x1.w};
    float o[8];
    #pragma unroll
    for (int j = 0; j < 8; ++j) {
        float gg = (av[j] + tv[j] - y[j]) * inv + xv[j];
        o[j] = gg > 0.f ? gg : 0.f;
    }
    *(float4*)(out + base)     = make_float4(o[0], o[1], o[2], o[3]);
    *(float4*)(out + base + 4) = make_float4(o[4], o[5], o[6], o[7]);
}

extern "C" void kernel_launch(void* const* d_in, const int* in_sizes, int n_in,
                              void* d_out, int out_size, void* d_ws, size_t ws_size,
                              hipStream_t stream) {
    const float* x    = (const float*)d_in[0];
    const float* W    = (const float*)d_in[1];
    const float* bias = (const float*)d_in[2];
    float* out = (float*)d_out;

    // ws: y16 64MB | Wpack 96KB | asum 2MB | tsum 1MB   (~70.3 MB)
    char* ws = (char*)d_ws;
    uint16_t* y16   = (uint16_t*)(ws);
    uint16_t* wpack = (uint16_t*)(ws + 67108864);
    float* asum     = (float*)(ws + 67108864 + 98304);
    float* tsum     = (float*)(ws + 67108864 + 98304 + 2097152);

    wpack_kernel<<<192,   256, 0, stream>>>(W, wpack);
    conv_kernel <<<2048,  256, 0, stream>>>(x, wpack, bias, y16, asum);
    tsum_kernel <<<128,   256, 0, stream>>>(y16, tsum);
    final_kernel<<<16384, 256, 0, stream>>>(x, y16, asum, tsum, out);
}

// Round 3
// 141.096 us; speedup vs baseline: 2.8251x; 1.0372x over previous
//
#include <hip/hip_runtime.h>
#include <stdint.h>

// B=32, L=128, A=64, C=128, KT=3.  scale = sqrt(190).
// Conv as GEMM over rows r = t*64+a; tap d reads x rows r + (d-1)*64.

typedef __attribute__((ext_vector_type(8))) short bf16x8;
typedef __attribute__((ext_vector_type(4))) float f32x4;

__device__ __forceinline__ uint32_t f2bf(float f) {
    union { float f; uint32_t u; } v; v.f = f;
    return (v.u + 0x7FFFu + ((v.u >> 16) & 1u)) >> 16;  // RNE
}
__device__ __forceinline__ float bf2f(uint32_t h) {
    union { uint32_t u; float f; } v; v.u = h << 16; return v.f;
}

// W fp32 [co][ci][kt] -> Wpack bf16 in exact MFMA B-fragment order:
// Wpack[((d*4+ks)*8 + nt)*64 + lane][i]  with ci = ks*32+(lane>>4)*8+i, co = nt*16+(lane&15)
__global__ void wpack_kernel(const float* __restrict__ W, uint16_t* __restrict__ wp) {
    int o = blockIdx.x * 256 + threadIdx.x;   // 192*256 = 49152 exact
    int i = o & 7, lane = (o >> 3) & 63, nt = (o >> 9) & 7, ks = (o >> 12) & 3, d = o >> 14;
    int ci = ks * 32 + (lane >> 4) * 8 + i;
    int co = nt * 16 + (lane & 15);
    wp[o] = (uint16_t)f2bf(W[(co * 128 + ci) * 3 + d]);
}

// One block per (b, t-pair): 128 rows x 128 co.  Slab: 256 rows x 64-ci chunk (36KB).
__global__ __launch_bounds__(256, 4) void conv_kernel(
    const float* __restrict__ x, const uint16_t* __restrict__ wp,
    const float* __restrict__ bias, uint16_t* __restrict__ y16,
    float* __restrict__ asum)
{
    __shared__ __align__(16) uint16_t lds[256 * 72];   // 36864 B; reused as bounce

    const int tid = threadIdx.x;
    const int bid = blockIdx.x;            // b*64 + tg
    const int b = bid >> 6, t0 = (bid & 63) * 2;

    const int lane = tid & 63, wid = tid >> 6;
    const int wm = wid >> 1, wn = wid & 1;
    const int lr = lane & 15, lg = lane >> 4;

    f32x4 acc[4][4];
    #pragma unroll
    for (int mi = 0; mi < 4; ++mi)
        #pragma unroll
        for (int ni = 0; ni < 4; ++ni) acc[mi][ni] = (f32x4)0.f;

    const int sr = tid >> 3;            // staging: row offset 0..31
    const int sc = (tid & 7) * 8;       // staging: ci within chunk

    #pragma unroll
    for (int cc = 0; cc < 2; ++cc) {
        const int ci0 = cc * 64;
        // ---- stage 256 rows x 64 ci (fp32 -> bf16), row stride 72 el (144B) ----
        #pragma unroll
        for (int p = 0; p < 8; ++p) {
            const int row  = p * 32 + sr;
            const int tloc = t0 + (row >> 6) - 1;
            uint4 o4 = make_uint4(0, 0, 0, 0);
            if ((unsigned)tloc < 128u) {
                const float* src = x + (((size_t)(b * 128 + tloc) * 64 + (row & 63)) * 128) + ci0 + sc;
                float4 v0 = *(const float4*)src;
                float4 v1 = *(const float4*)(src + 4);
                o4.x = f2bf(v0.x) | (f2bf(v0.y) << 16);
                o4.y = f2bf(v0.z) | (f2bf(v0.w) << 16);
                o4.z = f2bf(v1.x) | (f2bf(v1.y) << 16);
                o4.w = f2bf(v1.z) | (f2bf(v1.w) << 16);
            }
            *(uint4*)(lds + row * 72 + sc) = o4;
        }
        __syncthreads();

        // ---- MFMA over this 64-ci chunk (no barriers inside) ----
        #pragma unroll
        for (int d = 0; d < 3; ++d) {
            #pragma unroll
            for (int g2 = 0; g2 < 2; ++g2) {
                const int ks = cc * 2 + g2;
                const int cil = g2 * 32 + lg * 8;
                bf16x8 af[4], bfr[4];
                #pragma unroll
                for (int mi = 0; mi < 4; ++mi) {
                    const int row = (wm + d) * 64 + mi * 16 + lr;
                    af[mi] = *(const bf16x8*)(lds + row * 72 + cil);
                }
                #pragma unroll
                for (int ni = 0; ni < 4; ++ni)
                    bfr[ni] = *(const bf16x8*)(wp + ((((d * 4 + ks) * 8 + wn * 4 + ni) * 64 + lane) << 3));
                #pragma unroll
                for (int mi = 0; mi < 4; ++mi)
                    #pragma unroll
                    for (int ni = 0; ni < 4; ++ni)
                        acc[mi][ni] = __builtin_amdgcn_mfma_f32_16x16x32_bf16(af[mi], bfr[ni], acc[mi][ni], 0, 0, 0);
            }
        }
        __syncthreads();
    }

    // ---- epilogue: acc -> LDS bounce (stride 136 el) + agent_sum ----
    #pragma unroll
    for (int ni = 0; ni < 4; ++ni) {
        const int col = wn * 64 + ni * 16 + lr;
        const float bv = bias[col];
        float p = 0.f;
        #pragma unroll
        for (int mi = 0; mi < 4; ++mi) {
            #pragma unroll
            for (int j = 0; j < 4; ++j) {
                const float av = acc[mi][ni][j];
                p += av;
                const int row = wm * 64 + mi * 16 + lg * 4 + j;
                lds[row * 136 + col] = (uint16_t)f2bf(av + bv);
            }
        }
        p += __shfl_xor(p, 16);
        p += __shfl_xor(p, 32);
        if (lg == 0)
            asum[(size_t)(b * 128 + t0 + wm) * 128 + col] = p + 64.f * bv;
    }
    __syncthreads();

    // ---- coalesced y16 store: wave writes contiguous 1KB per iteration ----
    {
        const int rb = tid >> 4, cg = (tid & 15) * 8;
        const size_t ybase = (size_t)bid * 16384;
        #pragma unroll
        for (int j = 0; j < 8; ++j) {
            const int row = j * 16 + rb;
            const uint4 v = *(const uint4*)(lds + row * 136 + cg);
            *(uint4*)(y16 + ybase + row * 128 + cg) = v;
        }
    }
}

// time_sum[b][a][c] = sum_t y[b][t][a][c]
__global__ __launch_bounds__(256) void tsum_kernel(
    const uint16_t* __restrict__ y16, float* __restrict__ tsum)
{
    const int g = blockIdx.x * 256 + threadIdx.x;   // 128 blocks: 32*64*16
    const int c0 = (g & 15) * 8;
    const int a  = (g >> 4) & 63;
    const int b  = g >> 10;
    const uint16_t* p = y16 + ((size_t)(b * 128) * 64 + a) * 128 + c0;
    float s[8];
    #pragma unroll
    for (int j = 0; j < 8; ++j) s[j] = 0.f;
    #pragma unroll 4
    for (int t = 0; t < 128; ++t) {
        const uint4 v = *(const uint4*)(p + (size_t)t * 8192);
        s[0] += bf2f(v.x & 0xFFFFu); s[1] += bf2f(v.x >> 16);
        s[2] += bf2f(v.y & 0xFFFFu); s[3] += bf2f(v.y >> 16);
        s[4] += bf2f(v.z & 0xFFFFu); s[5] += bf2f(v.z >> 16);
        s[6] += bf2f(v.w & 0xFFFFu); s[7] += bf2f(v.w >> 16);
    }
    float* q = tsum + (size_t)(b * 64 + a) * 128 + c0;
    *(float4*)q       = make_float4(s[0], s[1], s[2], s[3]);
    *(float4*)(q + 4) = make_float4(s[4], s[5], s[6], s[7]);
}

// out = relu((asum + tsum - y)/sqrt(190) + x), [B,L,A,C]
__global__ __launch_bounds__(256) void final_kernel(
    const float* __restrict__ x, const uint16_t* __restrict__ y16,
    const float* __restrict__ asum, const float* __restrict__ tsum,
    float* __restrict__ out)
{
    const float inv = 0.07254762501100116f;  // 1/sqrt(190)
    const size_t base = ((size_t)blockIdx.x * 256 + threadIdx.x) * 8;
    const int c0 = (int)(base & 127);
    const int a  = (int)((base >> 7) & 63);
    const int bt = (int)(base >> 13);
    const int b  = bt >> 7;

    const uint4  yv = *(const uint4*)(y16 + base);
    const float4 x0 = *(const float4*)(x + base);
    const float4 x1 = *(const float4*)(x + base + 4);
    const float* ap = asum + (size_t)bt * 128 + c0;
    const float* tp = tsum + ((size_t)b * 64 + a) * 128 + c0;
    const float4 as0 = *(const float4*)ap,  as1 = *(const float4*)(ap + 4);
    const float4 ts0 = *(const float4*)tp,  ts1 = *(const float4*)(tp + 4);

    float y[8];
    y[0] = bf2f(yv.x & 0xFFFFu); y[1] = bf2f(yv.x >> 16);
    y[2] = bf2f(yv.y & 0xFFFFu); y[3] = bf2f(yv.y >> 16);
    y[4] = bf2f(yv.z & 0xFFFFu); y[5] = bf2f(yv.z >> 16);
    y[6] = bf2f(yv.w & 0xFFFFu); y[7] = bf2f(yv.w >> 16);
    const float av[8] = {as0.x, as0.y, as0.z, as0.w, as1.x, as1.y, as1.z, as1.w};
    const float tv[8] = {ts0.x, ts0.y, ts0.z, ts0.w, ts1.x, ts1.y, ts1.z, ts1.w};
    const float xv[8] = {x0.x, x0.y, x0.z, x0.w, x1.x, x1.y, x1.z, x1.w};
    float o[8];
    #pragma unroll
    for (int j = 0; j < 8; ++j) {
        float gg = (av[j] + tv[j] - y[j]) * inv + xv[j];
        o[j] = gg > 0.f ? gg : 0.f;
    }
    *(float4*)(out + base)     = make_float4(o[0], o[1], o[2], o[3]);
    *(float4*)(out + base + 4) = make_float4(o[4], o[5], o[6], o[7]);
}

extern "C" void kernel_launch(void* const* d_in, const int* in_sizes, int n_in,
                              void* d_out, int out_size, void* d_ws, size_t ws_size,
                              hipStream_t stream) {
    const float* x    = (const float*)d_in[0];
    const float* W    = (const float*)d_in[1];
    const float* bias = (const float*)d_in[2];
    float* out = (float*)d_out;

    // ws: y16 64MB | Wpack 96KB | asum 2MB | tsum 1MB
    char* ws = (char*)d_ws;
    uint16_t* y16   = (uint16_t*)(ws);
    uint16_t* wpack = (uint16_t*)(ws + 67108864);
    float* asum     = (float*)(ws + 67108864 + 98304);
    float* tsum     = (float*)(ws + 67108864 + 98304 + 2097152);

    wpack_kernel<<<192,   256, 0, stream>>>(W, wpack);
    conv_kernel <<<2048,  256, 0, stream>>>(x, wpack, bias, y16, asum);
    tsum_kernel <<<128,   256, 0, stream>>>(y16, tsum);
    final_kernel<<<16384, 256, 0, stream>>>(x, y16, asum, tsum, out);
}

// Round 4
// 137.232 us; speedup vs baseline: 2.9047x; 1.0282x over previous
//
#include <hip/hip_runtime.h>
#include <stdint.h>

// B=32, L=128, A=64, C=128, KT=3.  scale = sqrt(190).
// Conv as GEMM over rows r = t*64+a; tap d reads x rows r + (d-1)*64.

typedef __attribute__((ext_vector_type(8))) short bf16x8;
typedef __attribute__((ext_vector_type(4))) float f32x4;

__device__ __forceinline__ uint32_t f2bf(float f) {
    union { float f; uint32_t u; } v; v.f = f;
    return (v.u + 0x7FFFu + ((v.u >> 16) & 1u)) >> 16;  // RNE
}
__device__ __forceinline__ float bf2f(uint32_t h) {
    union { uint32_t u; float f; } v; v.u = h << 16; return v.f;
}
__device__ __forceinline__ uint32_t pk2(float lo, float hi) {
    return f2bf(lo) | (f2bf(hi) << 16);
}

// W fp32 [co][ci][kt] -> Wpack bf16 in exact MFMA B-fragment order:
// Wpack[((d*4+ks)*8 + nt)*64 + lane][i]  with ci = ks*32+(lane>>4)*8+i, co = nt*16+(lane&15)
__global__ void wpack_kernel(const float* __restrict__ W, uint16_t* __restrict__ wp) {
    int o = blockIdx.x * 256 + threadIdx.x;   // 192*256 = 49152 exact
    int i = o & 7, lane = (o >> 3) & 63, nt = (o >> 9) & 7, ks = (o >> 12) & 3, d = o >> 14;
    int ci = ks * 32 + (lane >> 4) * 8 + i;
    int co = nt * 16 + (lane & 15);
    wp[o] = (uint16_t)f2bf(W[(co * 128 + ci) * 3 + d]);
}

// One block per (b, t-pair): 128 output rows x 128 co.
// K split into 4 chunks of 32 ci; double-buffered 256row x 32ci bf16 slabs (stride 40 el).
__global__ __launch_bounds__(256, 3) void conv_kernel(
    const float* __restrict__ x, const uint16_t* __restrict__ wp,
    const float* __restrict__ bias, uint16_t* __restrict__ y16,
    float* __restrict__ asum)
{
    __shared__ __align__(16) uint16_t lds[20480];   // 40 KB: 2 slabs of 10240 el; reused as bounce

    const int tid = threadIdx.x;
    const int bid = blockIdx.x;            // b*64 + tg
    const int b = bid >> 6, t0 = (bid & 63) * 2;

    const int lane = tid & 63, wid = tid >> 6;
    const int wm = wid >> 1, wn = wid & 1;
    const int lr = lane & 15, lg = lane >> 4;

    // staging mapping: thread -> (a = r0s, ci-seg), pass p -> t = t0+p-1
    const int seg = (tid & 3) * 8;
    const int r0s = tid >> 2;
    const float* xb = x + (size_t)b * 1048576 + (size_t)r0s * 128 + seg;

    float4 h[4][2];
    f32x4 acc[4][4];
    #pragma unroll
    for (int mi = 0; mi < 4; ++mi)
        #pragma unroll
        for (int ni = 0; ni < 4; ++ni) acc[mi][ni] = (f32x4)0.f;

#define ISSUE(c) do {                                                          \
    _Pragma("unroll")                                                          \
    for (int p = 0; p < 4; ++p) {                                              \
        const int tloc = t0 + p - 1;                                           \
        if ((unsigned)tloc < 128u) {                                           \
            const float* s_ = xb + (size_t)tloc * 8192 + (c) * 32;             \
            h[p][0] = *(const float4*)s_;                                      \
            h[p][1] = *(const float4*)(s_ + 4);                                \
        } else {                                                               \
            h[p][0] = make_float4(0.f,0.f,0.f,0.f);                            \
            h[p][1] = make_float4(0.f,0.f,0.f,0.f);                            \
        }                                                                      \
    } } while (0)

#define COMMIT(buf) do {                                                       \
    _Pragma("unroll")                                                          \
    for (int p = 0; p < 4; ++p) {                                              \
        uint4 o_;                                                              \
        o_.x = pk2(h[p][0].x, h[p][0].y);                                      \
        o_.y = pk2(h[p][0].z, h[p][0].w);                                      \
        o_.z = pk2(h[p][1].x, h[p][1].y);                                      \
        o_.w = pk2(h[p][1].z, h[p][1].w);                                      \
        *(uint4*)(lds + (buf) * 10240 + (p * 64 + r0s) * 40 + seg) = o_;       \
    } } while (0)

#define MFMA_CHUNK(c, buf) do {                                                \
    _Pragma("unroll")                                                          \
    for (int d = 0; d < 3; ++d) {                                              \
        bf16x8 bq[4], af[4];                                                   \
        _Pragma("unroll")                                                      \
        for (int ni = 0; ni < 4; ++ni)                                         \
            bq[ni] = *(const bf16x8*)(wp +                                     \
                ((((d * 4 + (c)) * 8) + wn * 4 + ni) * 64 + lane) * 8);        \
        _Pragma("unroll")                                                      \
        for (int mi = 0; mi < 4; ++mi)                                         \
            af[mi] = *(const bf16x8*)(lds + (buf) * 10240 +                    \
                ((wm + d) * 64 + mi * 16 + lr) * 40 + lg * 8);                 \
        _Pragma("unroll")                                                      \
        for (int mi = 0; mi < 4; ++mi)                                         \
            _Pragma("unroll")                                                  \
            for (int ni = 0; ni < 4; ++ni)                                     \
                acc[mi][ni] = __builtin_amdgcn_mfma_f32_16x16x32_bf16(         \
                    af[mi], bq[ni], acc[mi][ni], 0, 0, 0);                     \
    } } while (0)

    ISSUE(0); COMMIT(0);
    ISSUE(1);
    __syncthreads();          // slab0 ready

    MFMA_CHUNK(0, 0);
    COMMIT(1);                // chunk1 -> buf1 (fresh buffer, no hazard)
    ISSUE(2);
    __syncthreads();          // buf1 ready; all done reading buf0

    MFMA_CHUNK(1, 1);
    COMMIT(0);                // chunk2 -> buf0
    ISSUE(3);
    __syncthreads();

    MFMA_CHUNK(2, 0);
    COMMIT(1);                // chunk3 -> buf1
    __syncthreads();

    MFMA_CHUNK(3, 1);
    __syncthreads();          // all reads done before bounce overwrites lds

#undef ISSUE
#undef COMMIT
#undef MFMA_CHUNK

    // ---- epilogue: acc -> LDS bounce (stride 136 el) + agent_sum ----
    #pragma unroll
    for (int ni = 0; ni < 4; ++ni) {
        const int col = wn * 64 + ni * 16 + lr;
        const float bv = bias[col];
        float p = 0.f;
        #pragma unroll
        for (int mi = 0; mi < 4; ++mi) {
            #pragma unroll
            for (int j = 0; j < 4; ++j) {
                const float av = acc[mi][ni][j];
                p += av;
                lds[(wm * 64 + mi * 16 + lg * 4 + j) * 136 + col] = (uint16_t)f2bf(av + bv);
            }
        }
        p += __shfl_xor(p, 16);
        p += __shfl_xor(p, 32);
        if (lg == 0)
            asum[(size_t)(b * 128 + t0 + wm) * 128 + col] = p + 64.f * bv;
    }
    __syncthreads();

    // ---- coalesced y16 store: wave writes contiguous 1KB per iteration ----
    {
        const int rb = tid >> 4, cg = (tid & 15) * 8;
        const size_t ybase = (size_t)bid * 16384;
        #pragma unroll
        for (int j = 0; j < 8; ++j) {
            const int row = j * 16 + rb;
            *(uint4*)(y16 + ybase + row * 128 + cg) = *(const uint4*)(lds + row * 136 + cg);
        }
    }
}

// time_sum[b][a][c] = sum_t y[b][t][a][c]
__global__ __launch_bounds__(256) void tsum_kernel(
    const uint16_t* __restrict__ y16, float* __restrict__ tsum)
{
    const int g = blockIdx.x * 256 + threadIdx.x;   // 128 blocks: 32*64*16
    const int c0 = (g & 15) * 8;
    const int a  = (g >> 4) & 63;
    const int b  = g >> 10;
    const uint16_t* p = y16 + ((size_t)(b * 128) * 64 + a) * 128 + c0;
    float s[8];
    #pragma unroll
    for (int j = 0; j < 8; ++j) s[j] = 0.f;
    #pragma unroll 4
    for (int t = 0; t < 128; ++t) {
        const uint4 v = *(const uint4*)(p + (size_t)t * 8192);
        s[0] += bf2f(v.x & 0xFFFFu); s[1] += bf2f(v.x >> 16);
        s[2] += bf2f(v.y & 0xFFFFu); s[3] += bf2f(v.y >> 16);
        s[4] += bf2f(v.z & 0xFFFFu); s[5] += bf2f(v.z >> 16);
        s[6] += bf2f(v.w & 0xFFFFu); s[7] += bf2f(v.w >> 16);
    }
    float* q = tsum + (size_t)(b * 64 + a) * 128 + c0;
    *(float4*)q       = make_float4(s[0], s[1], s[2], s[3]);
    *(float4*)(q + 4) = make_float4(s[4], s[5], s[6], s[7]);
}

// out = relu((asum + tsum - y)/sqrt(190) + x), [B,L,A,C]
__global__ __launch_bounds__(256) void final_kernel(
    const float* __restrict__ x, const uint16_t* __restrict__ y16,
    const float* __restrict__ asum, const float* __restrict__ tsum,
    float* __restrict__ out)
{
    const float inv = 0.07254762501100116f;  // 1/sqrt(190)
    const size_t base = ((size_t)blockIdx.x * 256 + threadIdx.x) * 8;
    const int c0 = (int)(base & 127);
    const int a  = (int)((base >> 7) & 63);
    const int bt = (int)(base >> 13);
    const int b  = bt >> 7;

    const uint4  yv = *(const uint4*)(y16 + base);
    const float4 x0 = *(const float4*)(x + base);
    const float4 x1 = *(const float4*)(x + base + 4);
    const float* ap = asum + (size_t)bt * 128 + c0;
    const float* tp = tsum + ((size_t)b * 64 + a) * 128 + c0;
    const float4 as0 = *(const float4*)ap,  as1 = *(const float4*)(ap + 4);
    const float4 ts0 = *(const float4*)tp,  ts1 = *(const float4*)(tp + 4);

    float y[8];
    y[0] = bf2f(yv.x & 0xFFFFu); y[1] = bf2f(yv.x >> 16);
    y[2] = bf2f(yv.y & 0xFFFFu); y[3] = bf2f(yv.y >> 16);
    y[4] = bf2f(yv.z & 0xFFFFu); y[5] = bf2f(yv.z >> 16);
    y[6] = bf2f(yv.w & 0xFFFFu); y[7] = bf2f(yv.w >> 16);
    const float av[8] = {as0.x, as0.y, as0.z, as0.w, as1.x, as1.y, as1.z, as1.w};
    const float tv[8] = {ts0.x, ts0.y, ts0.z, ts0.w, ts1.x, ts1.y, ts1.z, ts1.w};
    const float xv[8] = {x0.x, x0.y, x0.z, x0.w, x1.x, x1.y, x1.z, x1.w};
    float o[8];
    #pragma unroll
    for (int j = 0; j < 8; ++j) {
        float gg = (av[j] + tv[j] - y[j]) * inv + xv[j];
        o[j] = gg > 0.f ? gg : 0.f;
    }
    *(float4*)(out + base)     = make_float4(o[0], o[1], o[2], o[3]);
    *(float4*)(out + base + 4) = make_float4(o[4], o[5], o[6], o[7]);
}

extern "C" void kernel_launch(void* const* d_in, const int* in_sizes, int n_in,
                              void* d_out, int out_size, void* d_ws, size_t ws_size,
                              hipStream_t stream) {
    const float* x    = (const float*)d_in[0];
    const float* W    = (const float*)d_in[1];
    const float* bias = (const float*)d_in[2];
    float* out = (float*)d_out;

    // ws: y16 64MB | Wpack 96KB | asum 2MB | tsum 1MB
    char* ws = (char*)d_ws;
    uint16_t* y16   = (uint16_t*)(ws);
    uint16_t* wpack = (uint16_t*)(ws + 67108864);
    float* asum     = (float*)(ws + 67108864 + 98304);
    float* tsum     = (float*)(ws + 67108864 + 98304 + 2097152);

    wpack_kernel<<<192,   256, 0, stream>>>(W, wpack);
    conv_kernel <<<2048,  256, 0, stream>>>(x, wpack, bias, y16, asum);
    tsum_kernel <<<128,   256, 0, stream>>>(y16, tsum);
    final_kernel<<<16384, 256, 0, stream>>>(x, y16, asum, tsum, out);
}